// Round 11
// baseline (371.813 us; speedup 1.0000x reference)
//
#include <hip/hip_runtime.h>
#include <cstdint>

#define NN 16
#define W64 64
#define MT 64                    // M elements per workgroup
#define NSTAGE 17                // stage 0 = W1/f, stages 1..16 = graph nodes
#define IST 72                   // inpbuf row stride (halves): 144B -> 2-way max on b128 reads

typedef _Float16 half8   __attribute__((ext_vector_type(8)));
typedef _Float16 half16  __attribute__((ext_vector_type(16)));
typedef float    floatx4 __attribute__((ext_vector_type(4)));

// ================== compile-time graph (np.random.RandomState(0)) ==================
// Validated on-device R2/R6/R8/R9. Evaluated constexpr: masks fold, node tiles get
// live-range-compressed register slots.
struct GPlan {
    unsigned pred[NN];
    unsigned sinkmask;
    int slot[NSTAGE];            // slot[i]: node i (i<16); slot[16] = f
    int nslot;
};

constexpr unsigned mt_next(unsigned (&mt)[624], int &mti) {
    if (mti >= 624) {
        for (int i = 0; i < 624; ++i) {
            const unsigned y = (mt[i] & 0x80000000u) | (mt[(i + 1) % 624] & 0x7fffffffu);
            unsigned v = mt[(i + 397) % 624] ^ (y >> 1);
            if (y & 1u) v ^= 0x9908b0dfu;
            mt[i] = v;
        }
        mti = 0;
    }
    unsigned y = mt[mti++];
    y ^= y >> 11;
    y ^= (y << 7)  & 0x9d2c5680u;
    y ^= (y << 15) & 0xefc60000u;
    y ^= y >> 18;
    return y;
}
constexpr double mt_rnd(unsigned (&mt)[624], int &mti) {
    const unsigned a = mt_next(mt, mti) >> 5;
    const unsigned b = mt_next(mt, mti) >> 6;
    return (a * 67108864.0 + b) / 9007199254740992.0;
}
constexpr long mt_randint(unsigned (&mt)[624], int &mti, long n) {
    const unsigned long maxv = (unsigned long)n - 1;
    if (maxv == 0) return 0;
    unsigned long mask = maxv;
    mask |= mask >> 1;  mask |= mask >> 2;  mask |= mask >> 4;
    mask |= mask >> 8;  mask |= mask >> 16;
    unsigned long v = (unsigned long)mt_next(mt, mti) & mask;
    while (v > maxv) v = (unsigned long)mt_next(mt, mti) & mask;
    return (long)v;
}

constexpr GPlan build_plan() {
    GPlan P = {};
    unsigned mt[624] = {};
    mt[0] = 0u;
    for (int i = 1; i < 624; ++i)
        mt[i] = 1812433253u * (mt[i-1] ^ (mt[i-1] >> 30)) + (unsigned)i;
    int mti = 624;

    bool edge[NN][NN] = {};
    for (int i = 0; i < NN; ++i) {
        for (int d = 1; d <= 2; ++d) {
            int j = (i + d) & (NN - 1);
            if (mt_rnd(mt, mti) < 0.75) j = (int)mt_randint(mt, mti, NN);
            const int a = i < j ? i : j;
            const int b = i < j ? j : i;
            if (a != b) edge[a][b] = true;
        }
    }
    for (int a = 0; a < NN; ++a)
        for (int b = 0; b < NN; ++b)
            if (edge[a][b]) P.pred[b] |= 1u << a;
    for (int j = 1; j < NN; ++j) {
        if (!P.pred[j]) {
            const int a = (int)mt_randint(mt, mti, j);
            P.pred[j] |= 1u << a;
            edge[a][j] = true;
        }
    }
    unsigned succ[NN] = {};
    for (int a = 0; a < NN; ++a)
        for (int b = 0; b < NN; ++b)
            if (edge[a][b]) succ[a] |= 1u << b;
    for (int j = 0; j < NN; ++j)
        if (!succ[j]) P.sinkmask |= 1u << j;

    int lastuse[NSTAGE] = {};
    for (int v = 0; v < NSTAGE; ++v) lastuse[v] = -1;
    for (int j = 0; j < NN; ++j) {
        const unsigned pm = P.pred[j];
        if (pm == 0u) { if (j > lastuse[16]) lastuse[16] = j; }
        else for (int i = 0; i < NN; ++i)
            if (pm & (1u << i)) { if (j > lastuse[i]) lastuse[i] = j; }
    }
    for (int i = 0; i < NN; ++i)
        if (P.sinkmask & (1u << i)) lastuse[i] = 17;

    int defstage[NSTAGE] = {};
    for (int i = 0; i < NN; ++i) defstage[i] = i + 1;
    defstage[16] = 0;

    int nmax = 0;
    for (int s = 0; s <= 16; ++s) {
        const int w = (s == 0) ? 16 : (s - 1);
        bool busy[NSTAGE] = {};
        for (int v = 0; v < NSTAGE; ++v) {
            if (v == w) continue;
            if (defstage[v] < s && lastuse[v] >= s)
                busy[P.slot[v]] = true;
        }
        int k = 0;
        while (busy[k]) ++k;
        P.slot[w] = k;
        if (k + 1 > nmax) nmax = k + 1;
    }
    P.nslot = nmax;
    return P;
}

constexpr GPlan kPlan = build_plan();
constexpr int NSLOT = kPlan.nslot;

// ---------------- fast activations ----------------
__device__ __forceinline__ float act_tanh(float x)     { return 1.0f - 2.0f / (1.0f + __expf(2.0f * x)); }
__device__ __forceinline__ float act_elu(float x)      { return x > 0.0f ? x : __expf(x) - 1.0f; }
__device__ __forceinline__ float act_softplus(float x) { return fmaxf(x, 0.0f) + __logf(1.0f + __expf(-fabsf(x))); }
__device__ __forceinline__ float act_gauss(float x)    { return __expf(-0.5f * x * x); }

__device__ __forceinline__ float apply_act(int a, float x) {
    switch (a) {
        case 0:  return act_tanh(x);
        case 1:  return act_elu(x);
        case 2:  return act_softplus(x);
        case 3:  return __sinf(x);
        default: return act_gauss(x);
    }
}

__device__ __forceinline__ half8 cvt8(float4 a, float4 b) {
    half8 h;
    h[0]=(_Float16)a.x; h[1]=(_Float16)a.y; h[2]=(_Float16)a.z; h[3]=(_Float16)a.w;
    h[4]=(_Float16)b.x; h[5]=(_Float16)b.y; h[6]=(_Float16)b.z; h[7]=(_Float16)b.w;
    return h;
}

// ---------------- weight pre-conversion: fp32 -> fp16 into d_ws ----------------
// ws layout: stage 0 = W1[64][64], stage 1+j = gW[j][64][64]; [w'][k] row-major.
__global__ void convert_weights(const float* __restrict__ W1,
                                const float* __restrict__ gW,
                                _Float16* __restrict__ ws)
{
    const int i = blockIdx.x * 256 + threadIdx.x;
    if (i >= NSTAGE * 4096) return;
    const float v = (i < 4096) ? W1[i] : gW[i - 4096];
    ws[i] = (_Float16)v;
}

// ---------------- main fused kernel ----------------
// Barrier-free (inpbuf is wave-private; no inter-wave LDS sharing). R10 lesson:
// without any fence the compiler hoists the 17 stages' independent global
// B-loads, explodes pressure, spills hreg (258 MB scratch writes). Fix:
// __builtin_amdgcn_sched_barrier(0) at each stage boundary — compile-time
// fence, zero runtime cost, waves still slip freely.
template<bool F16W>
__global__ __launch_bounds__(256, 3) void inr_mfma_kernel(
    const float* __restrict__ inputs, const float* __restrict__ latents,
    const float* __restrict__ Wl, const float* __restrict__ bl,
    const float* __restrict__ Wx, const float* __restrict__ Wy,
    const float* __restrict__ Wr, const float* __restrict__ W1,
    const float* __restrict__ b1, const float* __restrict__ gW,
    const float* __restrict__ gB, const float* __restrict__ outW,
    const float* __restrict__ outb, const float* __restrict__ scale,
    const _Float16* __restrict__ wsW,
    float* __restrict__ out, int Btot)
{
    __shared__ __align__(16) _Float16 inpbuf[2][MT * IST];  // [slot][m*IST + k]

    const int tid  = threadIdx.x;
    const int lane = tid & 63;
    const int wv   = tid >> 6;            // wave id 0..3
    const int q    = lane >> 4;           // quad
    const int c    = lane & 15;           // col-in-tile
    const int rowbase = wv * 16;          // this wave's 16 M-rows within the tile
    const int m0   = blockIdx.x * MT;

    // node state in MFMA C-layout, slot-compressed:
    // hreg[kPlan.slot[n]][t*4+r] = h_n[m = rowbase+q*4+r][w' = t*16+c]
    half16 hreg[NSLOT];

    // ---- embed: g0[m][k] -> inpbuf[0]  (thread t: m = t>>2, k-range = (t&3)*16..+15)
    {
        const int em = tid >> 2, ep = tid & 3;
        int mg = m0 + em; if (mg >= Btot) mg = Btot - 1;
        const float x = inputs[mg * 3 + 0];
        const float y = inputs[mg * 3 + 1];
        const float r = inputs[mg * 3 + 2];
        const float4 l0 = *(const float4*)(latents + mg * 8);
        const float4 l1 = *(const float4*)(latents + mg * 8 + 4);
        #pragma unroll
        for (int i = 0; i < 16; ++i) {
            const int k = ep * 16 + i;
            const float4 a = *(const float4*)(Wl + k * 8);
            const float4 b = *(const float4*)(Wl + k * 8 + 4);
            float ld = bl[k];
            ld = fmaf(l0.x, a.x, ld); ld = fmaf(l0.y, a.y, ld);
            ld = fmaf(l0.z, a.z, ld); ld = fmaf(l0.w, a.w, ld);
            ld = fmaf(l1.x, b.x, ld); ld = fmaf(l1.y, b.y, ld);
            ld = fmaf(l1.z, b.z, ld); ld = fmaf(l1.w, b.w, ld);
            const float tk = act_tanh(x * Wx[k]) + act_softplus(y * Wy[k])
                           + act_elu(r * Wr[k]) + act_tanh(ld);
            inpbuf[0][em * IST + k] = (_Float16)act_gauss(tk);
        }
    }
    // no __syncthreads: em rows (tid>>2) are this thread's own wave's rows;
    // same-wave LDS RAW is ordered by lgkmcnt.

    // ---- stage loop (barrier-free; per-stage compile-time fence) ----
    #pragma unroll
    for (int s = 0; s < NSTAGE; ++s) {
        const int slot = s & 1;

        // A fragments: A[m=lane&15][k=quad*8+j], rows rowbase..rowbase+15
        const half8 a0 = *(const half8*)&inpbuf[slot][(rowbase + c) * IST +  0 + q * 8];
        const half8 a1 = *(const half8*)&inpbuf[slot][(rowbase + c) * IST + 32 + q * 8];

        // B fragments direct from global (row w' = t*16+c, k-cols q*8.. / 32+q*8..)
        const float* bias = (s == 0) ? b1 : (gB + (s - 1) * W64);
        floatx4 acc[4];
        #pragma unroll
        for (int t = 0; t < 4; ++t) {
            half8 b0, b1f;
            if constexpr (F16W) {
                const _Float16* wrow = wsW + (s * 64 + t * 16 + c) * 64;
                b0  = *(const half8*)(wrow + q * 8);
                b1f = *(const half8*)(wrow + 32 + q * 8);
            } else {
                const float* wrow = ((s == 0) ? W1 : (gW + (s - 1) * 4096))
                                  + (t * 16 + c) * 64;
                b0  = cvt8(*(const float4*)(wrow + q * 8),
                           *(const float4*)(wrow + q * 8 + 4));
                b1f = cvt8(*(const float4*)(wrow + 32 + q * 8),
                           *(const float4*)(wrow + 32 + q * 8 + 4));
            }
            const float bs = bias[t * 16 + c];
            floatx4 z = {bs, bs, bs, bs};        // bias folded into accumulator init
            z = __builtin_amdgcn_mfma_f32_16x16x32_f16(a0, b0, z, 0, 0, 0);
            z = __builtin_amdgcn_mfma_f32_16x16x32_f16(a1, b1f, z, 0, 0, 0);
            acc[t] = z;
        }

        // epilogue: activation -> hreg slot (C-layout, packed)
        const int an    = (s == 0) ? 3 : ((s - 1) % 5);        // stage0 act = sin
        const int hslot = kPlan.slot[(s == 0) ? 16 : (s - 1)]; // constexpr-folds
        #pragma unroll
        for (int t = 0; t < 4; ++t) {
            #pragma unroll
            for (int r = 0; r < 4; ++r) {
                const float v = apply_act(an, acc[t][r]);
                hreg[hslot][t * 4 + r] = (_Float16)v;
            }
        }

        // build next stage's input (packed fp16 pred-sum, masks fold statically)
        if (s + 1 < NSTAGE) {
            const unsigned pm = kPlan.pred[s];    // compile-time constant
            half16 sum;
            if (pm == 0u) {                       // source: input = f
                sum = hreg[kPlan.slot[16]];
            } else {
                #pragma unroll
                for (int v = 0; v < 16; ++v) sum[v] = (_Float16)0.0f;
                #pragma unroll
                for (int i = 0; i < NN; ++i) {
                    if (pm & (1u << i)) {         // dead branches removed
                        sum += hreg[kPlan.slot[i]];
                    }
                }
            }
            const int wslot = (s + 1) & 1;
            #pragma unroll
            for (int t = 0; t < 4; ++t)
                #pragma unroll
                for (int r = 0; r < 4; ++r)
                    inpbuf[wslot][(rowbase + q * 4 + r) * IST + t * 16 + c] =
                        sum[t * 4 + r];
            // wave-private rows; same-wave RAW ordered by lgkmcnt — no barrier
        }

        // compile-time fence: nothing (esp. next stage's B-loads) moves across.
        __builtin_amdgcn_sched_barrier(0);
    }

    // ---- head: agg over sinks, LDS round trip (wave-private), 3 dots, sigmoid ----
    {
        half16 sum;
        #pragma unroll
        for (int v = 0; v < 16; ++v) sum[v] = (_Float16)0.0f;
        #pragma unroll
        for (int j = 0; j < NN; ++j) {
            if (kPlan.sinkmask & (1u << j)) {     // folds statically
                sum += hreg[kPlan.slot[j]];
            }
        }
        #pragma unroll
        for (int t = 0; t < 4; ++t)
            #pragma unroll
            for (int r = 0; r < 4; ++r)
                inpbuf[1][(rowbase + q * 4 + r) * IST + t * 16 + c] = sum[t * 4 + r];
    }
    {
        const int em = tid >> 2, ep = tid & 3;    // em rows are own-wave rows
        float p0 = 0.f, p1 = 0.f, p2 = 0.f;
        #pragma unroll
        for (int h = 0; h < 2; ++h) {
            const half8 hv = *(const half8*)&inpbuf[1][em * IST + ep * 16 + h * 8];
            #pragma unroll
            for (int i = 0; i < 8; ++i) {
                const float av = (float)hv[i];
                const int k = ep * 16 + h * 8 + i;
                p0 = fmaf(av, outW[0 * W64 + k], p0);
                p1 = fmaf(av, outW[1 * W64 + k], p1);
                p2 = fmaf(av, outW[2 * W64 + k], p2);
            }
        }
        p0 += __shfl_xor(p0, 1); p0 += __shfl_xor(p0, 2);
        p1 += __shfl_xor(p1, 1); p1 += __shfl_xor(p1, 2);
        p2 += __shfl_xor(p2, 1); p2 += __shfl_xor(p2, 2);
        const int mg = m0 + em;
        if (ep < 3 && mg < Btot) {
            const float pr = (ep == 0) ? p0 : ((ep == 1) ? p1 : p2);
            const float res = (pr + outb[ep]) * scale[0];
            out[mg * 3 + ep] = 1.0f / (1.0f + __expf(-res));
        }
    }
}

extern "C" void kernel_launch(void* const* d_in, const int* in_sizes, int n_in,
                              void* d_out, int out_size, void* d_ws, size_t ws_size,
                              hipStream_t stream)
{
    const float* inputs  = (const float*)d_in[0];
    const float* latents = (const float*)d_in[1];
    const float* Wl      = (const float*)d_in[2];
    const float* bl      = (const float*)d_in[3];
    const float* Wx      = (const float*)d_in[4];
    const float* Wy      = (const float*)d_in[5];
    const float* Wr      = (const float*)d_in[6];
    const float* W1      = (const float*)d_in[7];
    const float* b1      = (const float*)d_in[8];
    const float* gW      = (const float*)d_in[9];
    const float* gB      = (const float*)d_in[10];
    const float* outW    = (const float*)d_in[11];
    const float* outb    = (const float*)d_in[12];
    const float* scale   = (const float*)d_in[13];
    float* out = (float*)d_out;

    const int Btot = in_sizes[0] / 3;
    const int blocks = (Btot + MT - 1) / MT;
    const size_t wbytes = (size_t)NSTAGE * 4096 * sizeof(_Float16);  // 139264

    if (ws_size >= wbytes) {
        _Float16* wsW = (_Float16*)d_ws;
        convert_weights<<<(NSTAGE * 4096 + 255) / 256, 256, 0, stream>>>(W1, gW, wsW);
        inr_mfma_kernel<true><<<blocks, 256, 0, stream>>>(
            inputs, latents, Wl, bl, Wx, Wy, Wr, W1, b1, gW, gB, outW, outb, scale,
            wsW, out, Btot);
    } else {
        inr_mfma_kernel<false><<<blocks, 256, 0, stream>>>(
            inputs, latents, Wl, bl, Wx, Wy, Wr, W1, b1, gW, gB, outW, outb, scale,
            (const _Float16*)nullptr, out, Btot);
    }
}

// Round 12
// 184.650 us; speedup vs baseline: 2.0136x; 2.0136x over previous
//
#include <hip/hip_runtime.h>
#include <cstdint>

#define NN 16
#define W64 64
#define MT 64                    // M elements per workgroup
#define NSTAGE 17                // stage 0 = W1/f, stages 1..16 = graph nodes
#define IST 72                   // inpbuf row stride (halves): 144B -> 2-way max on b128 reads
#define WST 72                   // wbuf row stride

typedef _Float16 half8   __attribute__((ext_vector_type(8)));
typedef _Float16 half16  __attribute__((ext_vector_type(16)));
typedef float    floatx4 __attribute__((ext_vector_type(4)));

// ================== compile-time graph (np.random.RandomState(0)) ==================
// Validated on-device R2/R6/R8/R9. Evaluated constexpr: masks fold, node tiles get
// live-range-compressed register slots.
struct GPlan {
    unsigned pred[NN];
    unsigned sinkmask;
    int slot[NSTAGE];            // slot[i]: node i (i<16); slot[16] = f
    int nslot;
};

constexpr unsigned mt_next(unsigned (&mt)[624], int &mti) {
    if (mti >= 624) {
        for (int i = 0; i < 624; ++i) {
            const unsigned y = (mt[i] & 0x80000000u) | (mt[(i + 1) % 624] & 0x7fffffffu);
            unsigned v = mt[(i + 397) % 624] ^ (y >> 1);
            if (y & 1u) v ^= 0x9908b0dfu;
            mt[i] = v;
        }
        mti = 0;
    }
    unsigned y = mt[mti++];
    y ^= y >> 11;
    y ^= (y << 7)  & 0x9d2c5680u;
    y ^= (y << 15) & 0xefc60000u;
    y ^= y >> 18;
    return y;
}
constexpr double mt_rnd(unsigned (&mt)[624], int &mti) {
    const unsigned a = mt_next(mt, mti) >> 5;
    const unsigned b = mt_next(mt, mti) >> 6;
    return (a * 67108864.0 + b) / 9007199254740992.0;
}
constexpr long mt_randint(unsigned (&mt)[624], int &mti, long n) {
    const unsigned long maxv = (unsigned long)n - 1;
    if (maxv == 0) return 0;
    unsigned long mask = maxv;
    mask |= mask >> 1;  mask |= mask >> 2;  mask |= mask >> 4;
    mask |= mask >> 8;  mask |= mask >> 16;
    unsigned long v = (unsigned long)mt_next(mt, mti) & mask;
    while (v > maxv) v = (unsigned long)mt_next(mt, mti) & mask;
    return (long)v;
}

constexpr GPlan build_plan() {
    GPlan P = {};
    unsigned mt[624] = {};
    mt[0] = 0u;
    for (int i = 1; i < 624; ++i)
        mt[i] = 1812433253u * (mt[i-1] ^ (mt[i-1] >> 30)) + (unsigned)i;
    int mti = 624;

    bool edge[NN][NN] = {};
    for (int i = 0; i < NN; ++i) {
        for (int d = 1; d <= 2; ++d) {
            int j = (i + d) & (NN - 1);
            if (mt_rnd(mt, mti) < 0.75) j = (int)mt_randint(mt, mti, NN);
            const int a = i < j ? i : j;
            const int b = i < j ? j : i;
            if (a != b) edge[a][b] = true;
        }
    }
    for (int a = 0; a < NN; ++a)
        for (int b = 0; b < NN; ++b)
            if (edge[a][b]) P.pred[b] |= 1u << a;
    for (int j = 1; j < NN; ++j) {
        if (!P.pred[j]) {
            const int a = (int)mt_randint(mt, mti, j);
            P.pred[j] |= 1u << a;
            edge[a][j] = true;
        }
    }
    unsigned succ[NN] = {};
    for (int a = 0; a < NN; ++a)
        for (int b = 0; b < NN; ++b)
            if (edge[a][b]) succ[a] |= 1u << b;
    for (int j = 0; j < NN; ++j)
        if (!succ[j]) P.sinkmask |= 1u << j;

    int lastuse[NSTAGE] = {};
    for (int v = 0; v < NSTAGE; ++v) lastuse[v] = -1;
    for (int j = 0; j < NN; ++j) {
        const unsigned pm = P.pred[j];
        if (pm == 0u) { if (j > lastuse[16]) lastuse[16] = j; }
        else for (int i = 0; i < NN; ++i)
            if (pm & (1u << i)) { if (j > lastuse[i]) lastuse[i] = j; }
    }
    for (int i = 0; i < NN; ++i)
        if (P.sinkmask & (1u << i)) lastuse[i] = 17;

    int defstage[NSTAGE] = {};
    for (int i = 0; i < NN; ++i) defstage[i] = i + 1;
    defstage[16] = 0;

    int nmax = 0;
    for (int s = 0; s <= 16; ++s) {
        const int w = (s == 0) ? 16 : (s - 1);
        bool busy[NSTAGE] = {};
        for (int v = 0; v < NSTAGE; ++v) {
            if (v == w) continue;
            if (defstage[v] < s && lastuse[v] >= s)
                busy[P.slot[v]] = true;
        }
        int k = 0;
        while (busy[k]) ++k;
        P.slot[w] = k;
        if (k + 1 > nmax) nmax = k + 1;
    }
    P.nslot = nmax;
    return P;
}

constexpr GPlan kPlan = build_plan();
constexpr int NSLOT = kPlan.nslot;

// ---------------- fast activations ----------------
__device__ __forceinline__ float act_tanh(float x)     { return 1.0f - 2.0f / (1.0f + __expf(2.0f * x)); }
__device__ __forceinline__ float act_elu(float x)      { return x > 0.0f ? x : __expf(x) - 1.0f; }
__device__ __forceinline__ float act_softplus(float x) { return fmaxf(x, 0.0f) + __logf(1.0f + __expf(-fabsf(x))); }
__device__ __forceinline__ float act_gauss(float x)    { return __expf(-0.5f * x * x); }

__device__ __forceinline__ float apply_act(int a, float x) {
    switch (a) {
        case 0:  return act_tanh(x);
        case 1:  return act_elu(x);
        case 2:  return act_softplus(x);
        case 3:  return __sinf(x);
        default: return act_gauss(x);
    }
}

__device__ __forceinline__ half8 cvt8(float4 a, float4 b) {
    half8 h;
    h[0]=(_Float16)a.x; h[1]=(_Float16)a.y; h[2]=(_Float16)a.z; h[3]=(_Float16)a.w;
    h[4]=(_Float16)b.x; h[5]=(_Float16)b.y; h[6]=(_Float16)b.z; h[7]=(_Float16)b.w;
    return h;
}

// ---------------- weight pre-conversion: fp32 -> fp16 into d_ws ----------------
// ws layout: stage 0 = W1[64][64], stage 1+j = gW[j][64][64]; [w'][k] row-major.
__global__ void convert_weights(const float* __restrict__ W1,
                                const float* __restrict__ gW,
                                _Float16* __restrict__ ws)
{
    const int i = blockIdx.x * 256 + threadIdx.x;
    if (i >= NSTAGE * 4096) return;
    const float v = (i < 4096) ? W1[i] : gW[i - 4096];
    ws[i] = (_Float16)v;
}

// ---------------- main fused kernel ----------------
// R9 structure (per-stage __syncthreads + LDS wbuf — the proven fence; R10/R11's
// global-B variant made the RA spill hreg wholesale: 258 MB scratch). Change vs
// R9: weights pre-converted to fp16 in d_ws -> staging is 2x uint4 load + 2x b128
// LDS store per thread, no cvt VALU; bias folded into MFMA accumulator init.
template<bool F16W>
__global__ __launch_bounds__(256, 3) void inr_mfma_kernel(
    const float* __restrict__ inputs, const float* __restrict__ latents,
    const float* __restrict__ Wl, const float* __restrict__ bl,
    const float* __restrict__ Wx, const float* __restrict__ Wy,
    const float* __restrict__ Wr, const float* __restrict__ W1,
    const float* __restrict__ b1, const float* __restrict__ gW,
    const float* __restrict__ gB, const float* __restrict__ outW,
    const float* __restrict__ outb, const float* __restrict__ scale,
    const _Float16* __restrict__ wsW,
    float* __restrict__ out, int Btot)
{
    __shared__ __align__(16) _Float16 inpbuf[2][MT * IST];  // [slot][m*IST + k]
    __shared__ __align__(16) _Float16 wbuf[2][W64 * WST];   // [slot][w'*WST + k]

    const int tid  = threadIdx.x;
    const int lane = tid & 63;
    const int wv   = tid >> 6;            // wave id 0..3
    const int q    = lane >> 4;           // quad
    const int c    = lane & 15;           // col-in-tile
    const int rowbase = wv * 16;          // this wave's 16 M-rows within the tile
    const int m0   = blockIdx.x * MT;

    // weight-staging decomposition: thread handles 8-half chunks tid and tid+256
    const int srow = tid >> 3;            // 0..31
    const int sc8  = tid & 7;             // chunk-in-row 0..7

    // node state in MFMA C-layout, slot-compressed:
    // hreg[kPlan.slot[n]][t*4+r] = h_n[m = rowbase+q*4+r][w' = t*16+c]
    half16 hreg[NSLOT];

    // ---- embed: g0[m][k] -> inpbuf[0]  (thread t: m = t>>2, k-range = (t&3)*16..+15)
    {
        const int em = tid >> 2, ep = tid & 3;
        int mg = m0 + em; if (mg >= Btot) mg = Btot - 1;
        const float x = inputs[mg * 3 + 0];
        const float y = inputs[mg * 3 + 1];
        const float r = inputs[mg * 3 + 2];
        const float4 l0 = *(const float4*)(latents + mg * 8);
        const float4 l1 = *(const float4*)(latents + mg * 8 + 4);
        #pragma unroll
        for (int i = 0; i < 16; ++i) {
            const int k = ep * 16 + i;
            const float4 a = *(const float4*)(Wl + k * 8);
            const float4 b = *(const float4*)(Wl + k * 8 + 4);
            float ld = bl[k];
            ld = fmaf(l0.x, a.x, ld); ld = fmaf(l0.y, a.y, ld);
            ld = fmaf(l0.z, a.z, ld); ld = fmaf(l0.w, a.w, ld);
            ld = fmaf(l1.x, b.x, ld); ld = fmaf(l1.y, b.y, ld);
            ld = fmaf(l1.z, b.z, ld); ld = fmaf(l1.w, b.w, ld);
            const float tk = act_tanh(x * Wx[k]) + act_softplus(y * Wy[k])
                           + act_elu(r * Wr[k]) + act_tanh(ld);
            inpbuf[0][em * IST + k] = (_Float16)act_gauss(tk);
        }
    }
    // ---- stage W1 into wbuf[0], padded rows ----
    if constexpr (F16W) {
        const uint4* src = (const uint4*)wsW;                 // stage 0, fp16
        const uint4 h0 = src[tid], h1 = src[tid + 256];
        *(uint4*)&wbuf[0][srow * WST + sc8 * 8]        = h0;
        *(uint4*)&wbuf[0][(srow + 32) * WST + sc8 * 8] = h1;
    } else {
        const float4* src = (const float4*)W1;
        const float4 f0 = src[2 * tid],       f1 = src[2 * tid + 1];
        const float4 f2 = src[2 * tid + 512], f3 = src[2 * tid + 513];
        *(half8*)&wbuf[0][srow * WST + sc8 * 8]        = cvt8(f0, f1);
        *(half8*)&wbuf[0][(srow + 32) * WST + sc8 * 8] = cvt8(f2, f3);
    }
    __syncthreads();

    // ---- stage loop ----
    #pragma unroll
    for (int s = 0; s < NSTAGE; ++s) {
        const int slot = s & 1;

        // prefetch next stage's W into regs; stage s+1 uses gW[s] (fp16: ws stage s+1)
        uint4  nh0 = {}, nh1 = {};
        float4 nf0 = {}, nf1 = {}, nf2 = {}, nf3 = {};
        if (s + 1 < NSTAGE) {
            if constexpr (F16W) {
                const uint4* src = (const uint4*)(wsW + (s + 1) * 4096);
                nh0 = src[tid]; nh1 = src[tid + 256];
            } else {
                const float4* src = (const float4*)(gW + s * 4096);
                nf0 = src[2 * tid];       nf1 = src[2 * tid + 1];
                nf2 = src[2 * tid + 512]; nf3 = src[2 * tid + 513];
            }
        }

        // A fragments: A[m=lane&15][k=quad*8+j], rows rowbase..rowbase+15
        const half8 a0 = *(const half8*)&inpbuf[slot][(rowbase + c) * IST +  0 + q * 8];
        const half8 a1 = *(const half8*)&inpbuf[slot][(rowbase + c) * IST + 32 + q * 8];

        // B fragments from wbuf (stored [w'][k], i.e. B^T rows) + MFMA
        const float* bias = (s == 0) ? b1 : (gB + (s - 1) * W64);
        floatx4 acc[4];
        #pragma unroll
        for (int t = 0; t < 4; ++t) {
            const half8 b0  = *(const half8*)&wbuf[slot][(t * 16 + c) * WST +  0 + q * 8];
            const half8 b1f = *(const half8*)&wbuf[slot][(t * 16 + c) * WST + 32 + q * 8];
            const float bs = bias[t * 16 + c];
            floatx4 z = {bs, bs, bs, bs};        // bias folded into accumulator init
            z = __builtin_amdgcn_mfma_f32_16x16x32_f16(a0, b0, z, 0, 0, 0);
            z = __builtin_amdgcn_mfma_f32_16x16x32_f16(a1, b1f, z, 0, 0, 0);
            acc[t] = z;
        }

        // epilogue: activation -> hreg slot (C-layout, packed)
        const int an    = (s == 0) ? 3 : ((s - 1) % 5);        // stage0 act = sin
        const int hslot = kPlan.slot[(s == 0) ? 16 : (s - 1)]; // constexpr-folds
        #pragma unroll
        for (int t = 0; t < 4; ++t) {
            #pragma unroll
            for (int r = 0; r < 4; ++r) {
                const float v = apply_act(an, acc[t][r]);
                hreg[hslot][t * 4 + r] = (_Float16)v;
            }
        }

        // build next stage's input (packed fp16 pred-sum, masks fold statically)
        if (s + 1 < NSTAGE) {
            const unsigned pm = kPlan.pred[s];    // compile-time constant
            half16 sum;
            if (pm == 0u) {                       // source: input = f
                sum = hreg[kPlan.slot[16]];
            } else {
                #pragma unroll
                for (int v = 0; v < 16; ++v) sum[v] = (_Float16)0.0f;
                #pragma unroll
                for (int i = 0; i < NN; ++i) {
                    if (pm & (1u << i)) {         // dead branches removed
                        sum += hreg[kPlan.slot[i]];
                    }
                }
            }
            const int wslot = (s + 1) & 1;
            #pragma unroll
            for (int t = 0; t < 4; ++t)
                #pragma unroll
                for (int r = 0; r < 4; ++r)
                    inpbuf[wslot][(rowbase + q * 4 + r) * IST + t * 16 + c] =
                        sum[t * 4 + r];
            if constexpr (F16W) {
                *(uint4*)&wbuf[wslot][srow * WST + sc8 * 8]        = nh0;
                *(uint4*)&wbuf[wslot][(srow + 32) * WST + sc8 * 8] = nh1;
            } else {
                *(half8*)&wbuf[wslot][srow * WST + sc8 * 8]        = cvt8(nf0, nf1);
                *(half8*)&wbuf[wslot][(srow + 32) * WST + sc8 * 8] = cvt8(nf2, nf3);
            }
        }
        __syncthreads();
    }

    // ---- head: agg over sinks (packed fp16), LDS round trip, 3 dots, sigmoid ----
    {
        half16 sum;
        #pragma unroll
        for (int v = 0; v < 16; ++v) sum[v] = (_Float16)0.0f;
        #pragma unroll
        for (int j = 0; j < NN; ++j) {
            if (kPlan.sinkmask & (1u << j)) {     // folds statically
                sum += hreg[kPlan.slot[j]];
            }
        }
        #pragma unroll
        for (int t = 0; t < 4; ++t)
            #pragma unroll
            for (int r = 0; r < 4; ++r)
                inpbuf[1][(rowbase + q * 4 + r) * IST + t * 16 + c] = sum[t * 4 + r];
    }
    __syncthreads();
    {
        const int em = tid >> 2, ep = tid & 3;
        float p0 = 0.f, p1 = 0.f, p2 = 0.f;
        #pragma unroll
        for (int h = 0; h < 2; ++h) {
            const half8 hv = *(const half8*)&inpbuf[1][em * IST + ep * 16 + h * 8];
            #pragma unroll
            for (int i = 0; i < 8; ++i) {
                const float av = (float)hv[i];
                const int k = ep * 16 + h * 8 + i;
                p0 = fmaf(av, outW[0 * W64 + k], p0);
                p1 = fmaf(av, outW[1 * W64 + k], p1);
                p2 = fmaf(av, outW[2 * W64 + k], p2);
            }
        }
        p0 += __shfl_xor(p0, 1); p0 += __shfl_xor(p0, 2);
        p1 += __shfl_xor(p1, 1); p1 += __shfl_xor(p1, 2);
        p2 += __shfl_xor(p2, 1); p2 += __shfl_xor(p2, 2);
        const int mg = m0 + em;
        if (ep < 3 && mg < Btot) {
            const float pr = (ep == 0) ? p0 : ((ep == 1) ? p1 : p2);
            const float res = (pr + outb[ep]) * scale[0];
            out[mg * 3 + ep] = 1.0f / (1.0f + __expf(-res));
        }
    }
}

extern "C" void kernel_launch(void* const* d_in, const int* in_sizes, int n_in,
                              void* d_out, int out_size, void* d_ws, size_t ws_size,
                              hipStream_t stream)
{
    const float* inputs  = (const float*)d_in[0];
    const float* latents = (const float*)d_in[1];
    const float* Wl      = (const float*)d_in[2];
    const float* bl      = (const float*)d_in[3];
    const float* Wx      = (const float*)d_in[4];
    const float* Wy      = (const float*)d_in[5];
    const float* Wr      = (const float*)d_in[6];
    const float* W1      = (const float*)d_in[7];
    const float* b1      = (const float*)d_in[8];
    const float* gW      = (const float*)d_in[9];
    const float* gB      = (const float*)d_in[10];
    const float* outW    = (const float*)d_in[11];
    const float* outb    = (const float*)d_in[12];
    const float* scale   = (const float*)d_in[13];
    float* out = (float*)d_out;

    const int Btot = in_sizes[0] / 3;
    const int blocks = (Btot + MT - 1) / MT;
    const size_t wbytes = (size_t)NSTAGE * 4096 * sizeof(_Float16);  // 139264

    if (ws_size >= wbytes) {
        _Float16* wsW = (_Float16*)d_ws;
        convert_weights<<<(NSTAGE * 4096 + 255) / 256, 256, 0, stream>>>(W1, gW, wsW);
        inr_mfma_kernel<true><<<blocks, 256, 0, stream>>>(
            inputs, latents, Wl, bl, Wx, Wy, Wr, W1, b1, gW, gB, outW, outb, scale,
            wsW, out, Btot);
    } else {
        inr_mfma_kernel<false><<<blocks, 256, 0, stream>>>(
            inputs, latents, Wl, bl, Wx, Wy, Wr, W1, b1, gW, gB, outW, outb, scale,
            (const _Float16*)nullptr, out, Btot);
    }
}

// Round 13
// 181.690 us; speedup vs baseline: 2.0464x; 1.0163x over previous
//
#include <hip/hip_runtime.h>
#include <cstdint>

#define NN 16
#define W64 64
#define MT 64                    // M elements per workgroup
#define NSTAGE 17                // stage 0 = W1/f, stages 1..16 = graph nodes
#define IST 72                   // inpbuf row stride (halves): 144B -> 2-way max on b128 reads
#define WST 68                   // wbuf row stride: 136B = 8 mod 128 -> 2-way on B-frag reads

typedef _Float16 half8   __attribute__((ext_vector_type(8)));
typedef _Float16 half16  __attribute__((ext_vector_type(16)));
typedef float    floatx4 __attribute__((ext_vector_type(4)));

// ================== compile-time graph (np.random.RandomState(0)) ==================
// Validated on-device R2/R6/R8/R9/R12. Constexpr: masks fold, node tiles get
// live-range-compressed register slots.
struct GPlan {
    unsigned pred[NN];
    unsigned sinkmask;
    int slot[NSTAGE];            // slot[i]: node i (i<16); slot[16] = f
    int nslot;
};

constexpr unsigned mt_next(unsigned (&mt)[624], int &mti) {
    if (mti >= 624) {
        for (int i = 0; i < 624; ++i) {
            const unsigned y = (mt[i] & 0x80000000u) | (mt[(i + 1) % 624] & 0x7fffffffu);
            unsigned v = mt[(i + 397) % 624] ^ (y >> 1);
            if (y & 1u) v ^= 0x9908b0dfu;
            mt[i] = v;
        }
        mti = 0;
    }
    unsigned y = mt[mti++];
    y ^= y >> 11;
    y ^= (y << 7)  & 0x9d2c5680u;
    y ^= (y << 15) & 0xefc60000u;
    y ^= y >> 18;
    return y;
}
constexpr double mt_rnd(unsigned (&mt)[624], int &mti) {
    const unsigned a = mt_next(mt, mti) >> 5;
    const unsigned b = mt_next(mt, mti) >> 6;
    return (a * 67108864.0 + b) / 9007199254740992.0;
}
constexpr long mt_randint(unsigned (&mt)[624], int &mti, long n) {
    const unsigned long maxv = (unsigned long)n - 1;
    if (maxv == 0) return 0;
    unsigned long mask = maxv;
    mask |= mask >> 1;  mask |= mask >> 2;  mask |= mask >> 4;
    mask |= mask >> 8;  mask |= mask >> 16;
    unsigned long v = (unsigned long)mt_next(mt, mti) & mask;
    while (v > maxv) v = (unsigned long)mt_next(mt, mti) & mask;
    return (long)v;
}

constexpr GPlan build_plan() {
    GPlan P = {};
    unsigned mt[624] = {};
    mt[0] = 0u;
    for (int i = 1; i < 624; ++i)
        mt[i] = 1812433253u * (mt[i-1] ^ (mt[i-1] >> 30)) + (unsigned)i;
    int mti = 624;

    bool edge[NN][NN] = {};
    for (int i = 0; i < NN; ++i) {
        for (int d = 1; d <= 2; ++d) {
            int j = (i + d) & (NN - 1);
            if (mt_rnd(mt, mti) < 0.75) j = (int)mt_randint(mt, mti, NN);
            const int a = i < j ? i : j;
            const int b = i < j ? j : i;
            if (a != b) edge[a][b] = true;
        }
    }
    for (int a = 0; a < NN; ++a)
        for (int b = 0; b < NN; ++b)
            if (edge[a][b]) P.pred[b] |= 1u << a;
    for (int j = 1; j < NN; ++j) {
        if (!P.pred[j]) {
            const int a = (int)mt_randint(mt, mti, j);
            P.pred[j] |= 1u << a;
            edge[a][j] = true;
        }
    }
    unsigned succ[NN] = {};
    for (int a = 0; a < NN; ++a)
        for (int b = 0; b < NN; ++b)
            if (edge[a][b]) succ[a] |= 1u << b;
    for (int j = 0; j < NN; ++j)
        if (!succ[j]) P.sinkmask |= 1u << j;

    int lastuse[NSTAGE] = {};
    for (int v = 0; v < NSTAGE; ++v) lastuse[v] = -1;
    for (int j = 0; j < NN; ++j) {
        const unsigned pm = P.pred[j];
        if (pm == 0u) { if (j > lastuse[16]) lastuse[16] = j; }
        else for (int i = 0; i < NN; ++i)
            if (pm & (1u << i)) { if (j > lastuse[i]) lastuse[i] = j; }
    }
    for (int i = 0; i < NN; ++i)
        if (P.sinkmask & (1u << i)) lastuse[i] = 17;

    int defstage[NSTAGE] = {};
    for (int i = 0; i < NN; ++i) defstage[i] = i + 1;
    defstage[16] = 0;

    int nmax = 0;
    for (int s = 0; s <= 16; ++s) {
        const int w = (s == 0) ? 16 : (s - 1);
        bool busy[NSTAGE] = {};
        for (int v = 0; v < NSTAGE; ++v) {
            if (v == w) continue;
            if (defstage[v] < s && lastuse[v] >= s)
                busy[P.slot[v]] = true;
        }
        int k = 0;
        while (busy[k]) ++k;
        P.slot[w] = k;
        if (k + 1 > nmax) nmax = k + 1;
    }
    P.nslot = nmax;
    return P;
}

constexpr GPlan kPlan = build_plan();
constexpr int NSLOT = kPlan.nslot;

// ---------------- fast activations ----------------
__device__ __forceinline__ float act_tanh(float x)     { return 1.0f - 2.0f / (1.0f + __expf(2.0f * x)); }
__device__ __forceinline__ float act_elu(float x)      { return x > 0.0f ? x : __expf(x) - 1.0f; }
__device__ __forceinline__ float act_softplus(float x) { return fmaxf(x, 0.0f) + __logf(1.0f + __expf(-fabsf(x))); }
__device__ __forceinline__ float act_gauss(float x)    { return __expf(-0.5f * x * x); }

__device__ __forceinline__ float apply_act(int a, float x) {
    switch (a) {
        case 0:  return act_tanh(x);
        case 1:  return act_elu(x);
        case 2:  return act_softplus(x);
        case 3:  return __sinf(x);
        default: return act_gauss(x);
    }
}

__device__ __forceinline__ half8 cvt8(float4 a, float4 b) {
    half8 h;
    h[0]=(_Float16)a.x; h[1]=(_Float16)a.y; h[2]=(_Float16)a.z; h[3]=(_Float16)a.w;
    h[4]=(_Float16)b.x; h[5]=(_Float16)b.y; h[6]=(_Float16)b.z; h[7]=(_Float16)b.w;
    return h;
}

// ---------------- weight pre-conversion: fp32 -> fp16 into d_ws ----------------
// ws layout: stage 0 = W1[64][64], stage 1+j = gW[j][64][64]; [w'][k] row-major.
__global__ void convert_weights(const float* __restrict__ W1,
                                const float* __restrict__ gW,
                                _Float16* __restrict__ ws)
{
    const int i = blockIdx.x * 256 + threadIdx.x;
    if (i >= NSTAGE * 4096) return;
    const float v = (i < 4096) ? W1[i] : gW[i - 4096];
    ws[i] = (_Float16)v;
}

// ---------------- main fused kernel ----------------
// R12 structure, but wbuf SINGLE-buffered (stride 68) to drop total LDS
// 36864 -> 27136 B (<= 32K target: 5 WG/CU by LDS). Two barriers/stage:
// B-frag reads at stage top -> MFMA/epilogue slack -> barrier1 (reads drained
// via compiler's lgkmcnt(0)-before-s_barrier) -> write W_{s+1} -> barrier2.
template<bool F16W>
__global__ __launch_bounds__(256, 3) void inr_mfma_kernel(
    const float* __restrict__ inputs, const float* __restrict__ latents,
    const float* __restrict__ Wl, const float* __restrict__ bl,
    const float* __restrict__ Wx, const float* __restrict__ Wy,
    const float* __restrict__ Wr, const float* __restrict__ W1,
    const float* __restrict__ b1, const float* __restrict__ gW,
    const float* __restrict__ gB, const float* __restrict__ outW,
    const float* __restrict__ outb, const float* __restrict__ scale,
    const _Float16* __restrict__ wsW,
    float* __restrict__ out, int Btot)
{
    __shared__ __align__(16) _Float16 inpbuf[2][MT * IST];  // [slot][m*IST + k]  18432 B
    __shared__ __align__(16) _Float16 wbuf[W64 * WST];      // single buffer      8704 B

    const int tid  = threadIdx.x;
    const int lane = tid & 63;
    const int wv   = tid >> 6;            // wave id 0..3
    const int q    = lane >> 4;           // quad
    const int c    = lane & 15;           // col-in-tile
    const int rowbase = wv * 16;          // this wave's 16 M-rows within the tile
    const int m0   = blockIdx.x * MT;

    // weight-staging decomposition: thread handles 8-half chunks tid and tid+256
    const int srow = tid >> 3;            // 0..31
    const int sc8  = tid & 7;             // chunk-in-row 0..7

    // node state in MFMA C-layout, slot-compressed:
    // hreg[kPlan.slot[n]][t*4+r] = h_n[m = rowbase+q*4+r][w' = t*16+c]
    half16 hreg[NSLOT];

    // ---- embed: g0[m][k] -> inpbuf[0]  (thread t: m = t>>2, k-range = (t&3)*16..+15)
    {
        const int em = tid >> 2, ep = tid & 3;
        int mg = m0 + em; if (mg >= Btot) mg = Btot - 1;
        const float x = inputs[mg * 3 + 0];
        const float y = inputs[mg * 3 + 1];
        const float r = inputs[mg * 3 + 2];
        const float4 l0 = *(const float4*)(latents + mg * 8);
        const float4 l1 = *(const float4*)(latents + mg * 8 + 4);
        #pragma unroll
        for (int i = 0; i < 16; ++i) {
            const int k = ep * 16 + i;
            const float4 a = *(const float4*)(Wl + k * 8);
            const float4 b = *(const float4*)(Wl + k * 8 + 4);
            float ld = bl[k];
            ld = fmaf(l0.x, a.x, ld); ld = fmaf(l0.y, a.y, ld);
            ld = fmaf(l0.z, a.z, ld); ld = fmaf(l0.w, a.w, ld);
            ld = fmaf(l1.x, b.x, ld); ld = fmaf(l1.y, b.y, ld);
            ld = fmaf(l1.z, b.z, ld); ld = fmaf(l1.w, b.w, ld);
            const float tk = act_tanh(x * Wx[k]) + act_softplus(y * Wy[k])
                           + act_elu(r * Wr[k]) + act_tanh(ld);
            inpbuf[0][em * IST + k] = (_Float16)act_gauss(tk);
        }
    }
    // ---- stage W1 into wbuf, padded rows ----
    if constexpr (F16W) {
        const uint4* src = (const uint4*)wsW;                 // stage 0, fp16
        const uint4 h0 = src[tid], h1 = src[tid + 256];
        *(uint4*)&wbuf[srow * WST + sc8 * 8]        = h0;
        *(uint4*)&wbuf[(srow + 32) * WST + sc8 * 8] = h1;
    } else {
        const float4* src = (const float4*)W1;
        const float4 f0 = src[2 * tid],       f1 = src[2 * tid + 1];
        const float4 f2 = src[2 * tid + 512], f3 = src[2 * tid + 513];
        *(half8*)&wbuf[srow * WST + sc8 * 8]        = cvt8(f0, f1);
        *(half8*)&wbuf[(srow + 32) * WST + sc8 * 8] = cvt8(f2, f3);
    }
    __syncthreads();

    // ---- stage loop ----
    #pragma unroll
    for (int s = 0; s < NSTAGE; ++s) {
        const int slot = s & 1;

        // prefetch next stage's W into regs (latency hidden across MFMA+epilogue)
        uint4  nh0 = {}, nh1 = {};
        float4 nf0 = {}, nf1 = {}, nf2 = {}, nf3 = {};
        if (s + 1 < NSTAGE) {
            if constexpr (F16W) {
                const uint4* src = (const uint4*)(wsW + (s + 1) * 4096);
                nh0 = src[tid]; nh1 = src[tid + 256];
            } else {
                const float4* src = (const float4*)(gW + s * 4096);
                nf0 = src[2 * tid];       nf1 = src[2 * tid + 1];
                nf2 = src[2 * tid + 512]; nf3 = src[2 * tid + 513];
            }
        }

        // A fragments: A[m=lane&15][k=quad*8+j], rows rowbase..rowbase+15
        const half8 a0 = *(const half8*)&inpbuf[slot][(rowbase + c) * IST +  0 + q * 8];
        const half8 a1 = *(const half8*)&inpbuf[slot][(rowbase + c) * IST + 32 + q * 8];

        // B fragments from wbuf (stored [w'][k], i.e. B^T rows) + MFMA
        const float* bias = (s == 0) ? b1 : (gB + (s - 1) * W64);
        floatx4 acc[4];
        #pragma unroll
        for (int t = 0; t < 4; ++t) {
            const half8 b0  = *(const half8*)&wbuf[(t * 16 + c) * WST +  0 + q * 8];
            const half8 b1f = *(const half8*)&wbuf[(t * 16 + c) * WST + 32 + q * 8];
            const float bs = bias[t * 16 + c];
            floatx4 z = {bs, bs, bs, bs};        // bias folded into accumulator init
            z = __builtin_amdgcn_mfma_f32_16x16x32_f16(a0, b0, z, 0, 0, 0);
            z = __builtin_amdgcn_mfma_f32_16x16x32_f16(a1, b1f, z, 0, 0, 0);
            acc[t] = z;
        }

        // epilogue: activation -> hreg slot (C-layout, packed)
        const int an    = (s == 0) ? 3 : ((s - 1) % 5);        // stage0 act = sin
        const int hslot = kPlan.slot[(s == 0) ? 16 : (s - 1)]; // constexpr-folds
        #pragma unroll
        for (int t = 0; t < 4; ++t) {
            #pragma unroll
            for (int r = 0; r < 4; ++r) {
                const float v = apply_act(an, acc[t][r]);
                hreg[hslot][t * 4 + r] = (_Float16)v;
            }
        }

        // build next stage's input (packed fp16 pred-sum, masks fold statically)
        if (s + 1 < NSTAGE) {
            const unsigned pm = kPlan.pred[s];    // compile-time constant
            half16 sum;
            if (pm == 0u) {                       // source: input = f
                sum = hreg[kPlan.slot[16]];
            } else {
                #pragma unroll
                for (int v = 0; v < 16; ++v) sum[v] = (_Float16)0.0f;
                #pragma unroll
                for (int i = 0; i < NN; ++i) {
                    if (pm & (1u << i)) {         // dead branches removed
                        sum += hreg[kPlan.slot[i]];
                    }
                }
            }
            const int wslot = (s + 1) & 1;
            #pragma unroll
            for (int t = 0; t < 4; ++t)
                #pragma unroll
                for (int r = 0; r < 4; ++r)
                    inpbuf[wslot][(rowbase + q * 4 + r) * IST + t * 16 + c] =
                        sum[t * 4 + r];

            // barrier1: all waves' wbuf B-frag reads are drained (lgkmcnt(0)
            // precedes s_barrier), safe to overwrite
            __syncthreads();
            if constexpr (F16W) {
                *(uint4*)&wbuf[srow * WST + sc8 * 8]        = nh0;
                *(uint4*)&wbuf[(srow + 32) * WST + sc8 * 8] = nh1;
            } else {
                *(half8*)&wbuf[srow * WST + sc8 * 8]        = cvt8(nf0, nf1);
                *(half8*)&wbuf[(srow + 32) * WST + sc8 * 8] = cvt8(nf2, nf3);
            }
            // barrier2: new weights visible to all waves
            __syncthreads();
        }
    }

    // ---- head: agg over sinks (packed fp16), LDS round trip, 3 dots, sigmoid ----
    {
        half16 sum;
        #pragma unroll
        for (int v = 0; v < 16; ++v) sum[v] = (_Float16)0.0f;
        #pragma unroll
        for (int j = 0; j < NN; ++j) {
            if (kPlan.sinkmask & (1u << j)) {     // folds statically
                sum += hreg[kPlan.slot[j]];
            }
        }
        #pragma unroll
        for (int t = 0; t < 4; ++t)
            #pragma unroll
            for (int r = 0; r < 4; ++r)
                inpbuf[1][(rowbase + q * 4 + r) * IST + t * 16 + c] = sum[t * 4 + r];
    }
    // inpbuf[1] rows are wave-private; same-wave RAW ordered by lgkmcnt
    {
        const int em = tid >> 2, ep = tid & 3;
        float p0 = 0.f, p1 = 0.f, p2 = 0.f;
        #pragma unroll
        for (int h = 0; h < 2; ++h) {
            const half8 hv = *(const half8*)&inpbuf[1][em * IST + ep * 16 + h * 8];
            #pragma unroll
            for (int i = 0; i < 8; ++i) {
                const float av = (float)hv[i];
                const int k = ep * 16 + h * 8 + i;
                p0 = fmaf(av, outW[0 * W64 + k], p0);
                p1 = fmaf(av, outW[1 * W64 + k], p1);
                p2 = fmaf(av, outW[2 * W64 + k], p2);
            }
        }
        p0 += __shfl_xor(p0, 1); p0 += __shfl_xor(p0, 2);
        p1 += __shfl_xor(p1, 1); p1 += __shfl_xor(p1, 2);
        p2 += __shfl_xor(p2, 1); p2 += __shfl_xor(p2, 2);
        const int mg = m0 + em;
        if (ep < 3 && mg < Btot) {
            const float pr = (ep == 0) ? p0 : ((ep == 1) ? p1 : p2);
            const float res = (pr + outb[ep]) * scale[0];
            out[mg * 3 + ep] = 1.0f / (1.0f + __expf(-res));
        }
    }
}

extern "C" void kernel_launch(void* const* d_in, const int* in_sizes, int n_in,
                              void* d_out, int out_size, void* d_ws, size_t ws_size,
                              hipStream_t stream)
{
    const float* inputs  = (const float*)d_in[0];
    const float* latents = (const float*)d_in[1];
    const float* Wl      = (const float*)d_in[2];
    const float* bl      = (const float*)d_in[3];
    const float* Wx      = (const float*)d_in[4];
    const float* Wy      = (const float*)d_in[5];
    const float* Wr      = (const float*)d_in[6];
    const float* W1      = (const float*)d_in[7];
    const float* b1      = (const float*)d_in[8];
    const float* gW      = (const float*)d_in[9];
    const float* gB      = (const float*)d_in[10];
    const float* outW    = (const float*)d_in[11];
    const float* outb    = (const float*)d_in[12];
    const float* scale   = (const float*)d_in[13];
    float* out = (float*)d_out;

    const int Btot = in_sizes[0] / 3;
    const int blocks = (Btot + MT - 1) / MT;
    const size_t wbytes = (size_t)NSTAGE * 4096 * sizeof(_Float16);  // 139264

    if (ws_size >= wbytes) {
        _Float16* wsW = (_Float16*)d_ws;
        convert_weights<<<(NSTAGE * 4096 + 255) / 256, 256, 0, stream>>>(W1, gW, wsW);
        inr_mfma_kernel<true><<<blocks, 256, 0, stream>>>(
            inputs, latents, Wl, bl, Wx, Wy, Wr, W1, b1, gW, gB, outW, outb, scale,
            wsW, out, Btot);
    } else {
        inr_mfma_kernel<false><<<blocks, 256, 0, stream>>>(
            inputs, latents, Wl, bl, Wx, Wy, Wr, W1, b1, gW, gB, outW, outb, scale,
            (const _Float16*)nullptr, out, Btot);
    }
}